// Round 2
// baseline (4110.369 us; speedup 1.0000x reference)
//
#include <hip/hip_runtime.h>

// Ocean advection + 3x3 binomial smoothing, 48 steps, fp32.
// k=3 steps fused per kernel: stage T0(halo 8W/6H), ug/vg/mask(halo 8W/5H) into
// LDS with float4 loads, then advect->smooth x3 fully in LDS with shrinking
// valid ranges, ping-pong aliasing two LDS buffers. 16 dispatches total.

#define DEG2RAD 0.017453292519943295f
#define R_EARTH 6371000.0f
#define DT_S 600.0f

constexpr int TW   = 64;     // output tile width (W)
constexpr int TH   = 32;     // output tile height (H)
constexpr int NT   = 256;    // threads per block
constexpr int SW   = 80;     // LDS row stride = TW + 16 (W-halo 8 each side, f4 aligned)
constexpr int WOFF = 8;      // LDS col 0 == global col w0-8
constexpr int RT   = 44;     // bufT rows  (T0: H-halo 6)
constexpr int RU   = 42;     // ug/vg/mask/C rows (H-halo 5)

__global__ __launch_bounds__(256)
void prep_kernel(const float* __restrict__ lat, const float* __restrict__ lon,
                 float* __restrict__ coef, int H) {
    int h = blockIdx.x * blockDim.x + threadIdx.x;
    if (h < H) {
        float dlon = lon[1] - lon[0];
        coef[h] = 1.0f / (R_EARTH * DEG2RAD * dlon * cosf(lat[h] * DEG2RAD));
    }
    if (h == 0) {
        float dlat = lat[1] - lat[0];
        coef[H] = 1.0f / (R_EARTH * DEG2RAD * dlat);
    }
}

// Stage src tile rows [h0+OH, h0+OH+RN) x cols [w0-8, w0+72) into dst (stride SW).
template<int RN, int OH>
__device__ inline void stage(float* __restrict__ dst, const float* __restrict__ src,
                             int h0, int w0, int H, int W, bool wfast, int tid) {
    if (wfast) {
        for (int i = tid; i < RN * (SW / 4); i += NT) {
            int r = i / (SW / 4), c4 = i - r * (SW / 4);
            int gh = min(max(h0 + OH + r, 0), H - 1);
            float4 v = *(const float4*)(src + (size_t)gh * W + (w0 - WOFF) + 4 * c4);
            *(float4*)(dst + r * SW + 4 * c4) = v;
        }
    } else {
        for (int i = tid; i < RN * SW; i += NT) {
            int r = i / SW, c = i - r * SW;
            int gh = min(max(h0 + OH + r, 0), H - 1);
            int gw = min(max(w0 - WOFF + c, 0), W - 1);
            dst[r * SW + c] = src[(size_t)gh * W + gw];
        }
    }
}

// Advect: dst = T + DT*F over rows [h0+H0, +R) x cols [w0+W0, +Cn); 0 outside domain.
// srcT row origin SORG (LDS row = gh-h0+SORG), dst row origin DORG. ug/vg/mask org 5.
template<int R, int Cn, int H0, int W0, int DORG, int SORG>
__device__ inline void advect(float* __restrict__ dst, const float* __restrict__ srcT,
                              const float* __restrict__ sUG, const float* __restrict__ sVG,
                              const float* __restrict__ sM, const float* __restrict__ sDX,
                              int h0, int w0, int H, int W, float inv_dy, int tid) {
    for (int i = tid; i < R * Cn; i += NT) {
        int r = i / Cn, c = i - r * Cn;
        int gh = h0 + H0 + r, gw = w0 + W0 + c;
        int dc = W0 + c + WOFF;
        float v = 0.0f;
        if (gh >= 0 && gh < H && gw >= 0 && gw < W) {
            int lc  = dc;
            int lrS = gh - h0 + SORG;
            int lcm = max(gw - 1, 0)     - w0 + WOFF;
            int lcp = min(gw + 1, W - 1) - w0 + WOFF;
            int lrm = max(gh - 1, 0)     - h0 + SORG;
            int lrp = min(gh + 1, H - 1) - h0 + SORG;
            float ndx = srcT[lrS * SW + lcp] - srcT[lrS * SW + lcm];
            float ndy = srcT[lrp * SW + lc]  - srcT[lrm * SW + lc];
            float sy = (gh == 0 || gh == H - 1) ? inv_dy : 0.5f * inv_dy;
            float ix = sDX[gh - h0 + 6];
            float sx = (gw == 0 || gw == W - 1) ? ix : 0.5f * ix;
            int lrG = gh - h0 + 5;
            float m = sM[lrG * SW + lc];
            float F = -(sUG[lrG * SW + lc] * (ndx * sx) + sVG[lrG * SW + lc] * (ndy * sy)) * m;
            v = srcT[lrS * SW + lc] + DT_S * F;
        }
        dst[(H0 + r + DORG) * SW + dc] = v;
    }
}

// Smooth: dst = conv3x3(src)/16 * mask over rows [h0+H0,+R) x cols [w0+W0,+Cn); 0 outside.
template<int R, int Cn, int H0, int W0, int DORG, int SORG>
__device__ inline void smoothp(float* __restrict__ dst, const float* __restrict__ src,
                               const float* __restrict__ sM,
                               int h0, int w0, int H, int W, int tid) {
    for (int i = tid; i < R * Cn; i += NT) {
        int r = i / Cn, c = i - r * Cn;
        int gh = h0 + H0 + r, gw = w0 + W0 + c;
        int dc = W0 + c + WOFF;
        int sr = H0 + r + SORG;
        float v = 0.0f;
        if (gh >= 0 && gh < H && gw >= 0 && gw < W) {
            const float* p0 = src + (sr - 1) * SW + dc;
            const float* p1 = src + sr * SW + dc;
            const float* p2 = src + (sr + 1) * SW + dc;
            float s = (p0[-1] + p0[1] + p2[-1] + p2[1])
                    + 2.0f * (p0[0] + p2[0] + p1[-1] + p1[1])
                    + 4.0f * p1[0];
            v = s * 0.0625f * sM[(gh - h0 + 5) * SW + dc];
        }
        dst[(H0 + r + DORG) * SW + dc] = v;
    }
}

__global__ __launch_bounds__(256)
void step3_kernel(const float* __restrict__ Tin, const float* __restrict__ ug,
                  const float* __restrict__ vg, const float* __restrict__ mask,
                  const float* __restrict__ coef, float* __restrict__ Tout,
                  int H, int W) {
    __shared__ float bufT[RT * SW];   // T0 (org 6) -> T1 (org 4) -> T2 (org 2)
    __shared__ float bufC[RU * SW];   // C1 (org 5) -> C2 (org 3) -> C3 (org 1)
    __shared__ float sUG[RU * SW], sVG[RU * SW], sM[RU * SW];  // org 5
    __shared__ float sDX[RT];

    const int tid = threadIdx.x;
    const int w0 = blockIdx.x * TW;
    const int h0 = blockIdx.y * TH;
    const int b  = blockIdx.z;
    const size_t plane = (size_t)H * W;
    const bool wfast = (w0 - WOFF >= 0) && (w0 - WOFF + SW <= W);

    const float inv_dy = coef[H];

    stage<RT, -6>(bufT, Tin + b * plane, h0, w0, H, W, wfast, tid);
    stage<RU, -5>(sUG,  ug  + b * plane, h0, w0, H, W, wfast, tid);
    stage<RU, -5>(sVG,  vg  + b * plane, h0, w0, H, W, wfast, tid);
    stage<RU, -5>(sM,   mask,            h0, w0, H, W, wfast, tid);
    if (tid < RT) {
        int gh = min(max(h0 - 6 + tid, 0), H - 1);
        sDX[tid] = coef[gh];
    }
    __syncthreads();

    // step 1
    advect <RU, 78, -5, -7, 5, 6>(bufC, bufT, sUG, sVG, sM, sDX, h0, w0, H, W, inv_dy, tid);
    __syncthreads();
    smoothp<40, 76, -4, -6, 4, 5>(bufT, bufC, sM, h0, w0, H, W, tid);
    __syncthreads();
    // step 2
    advect <38, 74, -3, -5, 3, 4>(bufC, bufT, sUG, sVG, sM, sDX, h0, w0, H, W, inv_dy, tid);
    __syncthreads();
    smoothp<36, 72, -2, -4, 2, 3>(bufT, bufC, sM, h0, w0, H, W, tid);
    __syncthreads();
    // step 3
    advect <34, 70, -1, -3, 1, 2>(bufC, bufT, sUG, sVG, sM, sDX, h0, w0, H, W, inv_dy, tid);
    __syncthreads();

    // final smooth -> global, float4 stores (C3 org 1, zeros outside domain = conv pad)
    float* __restrict__ To = Tout + b * plane;
    for (int i = tid; i < TH * (TW / 4); i += NT) {
        int r = i >> 4, c4 = (i & 15) * 4;
        int gh = h0 + r, gw0 = w0 + c4;
        if (gh < H && gw0 + 3 < W) {
            int sr = r + 1;
            float4 o;
            float* po = &o.x;
            #pragma unroll
            for (int j = 0; j < 4; ++j) {
                int dc = c4 + j + WOFF;
                const float* p0 = bufC + (sr - 1) * SW + dc;
                const float* p1 = bufC + sr * SW + dc;
                const float* p2 = bufC + (sr + 1) * SW + dc;
                float s = (p0[-1] + p0[1] + p2[-1] + p2[1])
                        + 2.0f * (p0[0] + p2[0] + p1[-1] + p1[1])
                        + 4.0f * p1[0];
                po[j] = s * 0.0625f * sM[(r + 5) * SW + dc];
            }
            *(float4*)(To + (size_t)gh * W + gw0) = o;
        }
    }
}

extern "C" void kernel_launch(void* const* d_in, const int* in_sizes, int n_in,
                              void* d_out, int out_size, void* d_ws, size_t ws_size,
                              hipStream_t stream) {
    const float* T0   = (const float*)d_in[0];
    const float* ug   = (const float*)d_in[1];
    const float* vg   = (const float*)d_in[2];
    const float* lat  = (const float*)d_in[3];
    const float* lon  = (const float*)d_in[4];
    const float* mask = (const float*)d_in[5];

    const int H = in_sizes[3];
    const int W = in_sizes[4];
    const int B = in_sizes[0] / (H * W);

    float* out  = (float*)d_out;
    float* ping = (float*)d_ws;                     // B*H*W floats
    float* coef = ping + (size_t)B * H * W;         // H+1 floats: 1/dx[h], then 1/dy

    prep_kernel<<<dim3((H + NT - 1) / NT), dim3(NT), 0, stream>>>(lat, lon, coef, H);

    dim3 grid((W + TW - 1) / TW, (H + TH - 1) / TH, B);
    const int NLAUNCH = 16;   // 16 x 3 fused steps = 48
    for (int i = 0; i < NLAUNCH; ++i) {
        const float* src = (i == 0) ? T0 : ((i & 1) ? ping : out);
        float*       dst = (i & 1) ? out : ping;
        step3_kernel<<<grid, dim3(NT), 0, stream>>>(src, ug, vg, mask, coef, dst, H, W);
    }
}

// Round 3
// 1989.557 us; speedup vs baseline: 2.0660x; 2.0660x over previous
//
#include <hip/hip_runtime.h>

// Ocean advection + 3x3 binomial smoothing, 48 steps, fp32.
// One step per kernel (round-1 structure: stage T -> advect into LDS -> smooth),
// fully float4-vectorized: staging, ug/vg/mask loads, aligned b128 LDS reads
// with register shifts, float4 stores. Tile 128x16, ~22KB LDS, 7 blocks/CU.

#define DEG2RAD 0.017453292519943295f
#define R_EARTH 6371000.0f
#define DT_S 600.0f

constexpr int TW   = 128;    // output tile width (W)
constexpr int TH   = 16;     // output tile height (H)
constexpr int NT   = 256;    // threads per block
constexpr int SW   = 144;    // LDS row stride = TW + 16
constexpr int WOFF = 8;      // LDS col 0 == global col w0-8
constexpr int RT   = TH + 4; // 20 sT rows, row 0 = gh h0-2
constexpr int RM   = TH + 2; // 18 sMid rows, row 0 = gh h0-1

__global__ __launch_bounds__(256)
void prep_kernel(const float* __restrict__ lat, const float* __restrict__ lon,
                 float* __restrict__ coef, int H) {
    int h = blockIdx.x * blockDim.x + threadIdx.x;
    if (h < H) {
        float dlon = lon[1] - lon[0];
        coef[h] = 1.0f / (R_EARTH * DEG2RAD * dlon * cosf(lat[h] * DEG2RAD));
    }
    if (h == 0) {
        float dlat = lat[1] - lat[0];
        coef[H] = 1.0f / (R_EARTH * DEG2RAD * dlat);
    }
}

__global__ __launch_bounds__(256)
void step_kernel(const float* __restrict__ Tin, const float* __restrict__ ug,
                 const float* __restrict__ vg, const float* __restrict__ mask,
                 const float* __restrict__ coef, float* __restrict__ Tout,
                 int H, int W) {
    __shared__ float sT[RT * SW];
    __shared__ float sM[RM * SW];

    const int tid = threadIdx.x;
    const int w0 = blockIdx.x * TW;
    const int h0 = blockIdx.y * TH;
    const int b  = blockIdx.z;
    const size_t plane = (size_t)H * W;
    const float* __restrict__ Tb  = Tin + b * plane;
    const float* __restrict__ ugb = ug  + b * plane;
    const float* __restrict__ vgb = vg  + b * plane;
    float* __restrict__ To = Tout + b * plane;
    const float inv_dy = coef[H];
    const bool wfast = (w0 - WOFF >= 0) && (w0 - WOFF + SW <= W) && ((W & 3) == 0);

    if (wfast) {
        // ---- stage T: rows [h0-2, h0+18), cols [w0-8, w0+136), float4 ----
        for (int i = tid; i < RT * (SW / 4); i += NT) {
            int r = i / (SW / 4), c4 = i - r * (SW / 4);
            int gh = min(max(h0 - 2 + r, 0), H - 1);
            *(float4*)(sT + r * SW + 4 * c4) =
                *(const float4*)(Tb + (size_t)gh * W + (w0 - WOFF) + 4 * c4);
        }
        __syncthreads();

        // ---- advect: 18 rows x 34 f4 (cols [w0-4, w0+132)) ----
        for (int i = tid; i < RM * 34; i += NT) {
            int r = i / 34, c4 = i - r * 34;
            int gh = h0 - 1 + r;
            int lc = 4 + 4 * c4;
            float4 v = {0.f, 0.f, 0.f, 0.f};
            if (gh >= 0 && gh < H) {
                int sr  = r + 1;
                int srm = max(gh - 1, 0) - h0 + 2;
                int srp = min(gh + 1, H - 1) - h0 + 2;
                float4 cC = *(float4*)(sT + sr * SW + lc);
                float4 cL = *(float4*)(sT + sr * SW + lc - 4);
                float4 cR = *(float4*)(sT + sr * SW + lc + 4);
                float4 cU = *(float4*)(sT + srm * SW + lc);
                float4 cD = *(float4*)(sT + srp * SW + lc);
                float sy = (gh == 0 || gh == H - 1) ? inv_dy : 0.5f * inv_dy;
                float sx = 0.5f * coef[gh];        // fast path: no W edges
                size_t gi = (size_t)gh * W + (w0 - 4 + 4 * c4);
                float4 u4 = *(const float4*)(ugb + gi);
                float4 g4 = *(const float4*)(vgb + gi);
                float4 m4 = *(const float4*)(mask + gi);
                float ndx0 = cC.y - cL.w, ndx1 = cC.z - cC.x;
                float ndx2 = cC.w - cC.y, ndx3 = cR.x - cC.z;
                v.x = cC.x + DT_S * (-(u4.x * (ndx0 * sx) + g4.x * ((cD.x - cU.x) * sy)) * m4.x);
                v.y = cC.y + DT_S * (-(u4.y * (ndx1 * sx) + g4.y * ((cD.y - cU.y) * sy)) * m4.y);
                v.z = cC.z + DT_S * (-(u4.z * (ndx2 * sx) + g4.z * ((cD.z - cU.z) * sy)) * m4.z);
                v.w = cC.w + DT_S * (-(u4.w * (ndx3 * sx) + g4.w * ((cD.w - cU.w) * sy)) * m4.w);
            }
            *(float4*)(sM + r * SW + lc) = v;
        }
        __syncthreads();

        // ---- smooth: 16 rows x 32 f4 -> global ----
        for (int i = tid; i < TH * 32; i += NT) {
            int r = i >> 5, c4 = i & 31;
            int gh = h0 + r;
            int lc = WOFF + 4 * c4;
            int sr = r + 1;
            const float* pU = sM + (sr - 1) * SW + lc;
            const float* pC = sM + sr * SW + lc;
            const float* pD = sM + (sr + 1) * SW + lc;
            float4 bU = *(const float4*)pU, bC = *(const float4*)pC, bD = *(const float4*)pD;
            float vC0 = bU.x + 2.f * bC.x + bD.x;
            float vC1 = bU.y + 2.f * bC.y + bD.y;
            float vC2 = bU.z + 2.f * bC.z + bD.z;
            float vC3 = bU.w + 2.f * bC.w + bD.w;
            float vL = pU[-1] + 2.f * pC[-1] + pD[-1];
            float vR = pU[4]  + 2.f * pC[4]  + pD[4];
            size_t gi = (size_t)gh * W + w0 + 4 * c4;
            float4 m4 = *(const float4*)(mask + gi);
            float4 o;
            o.x = (vL  + 2.f * vC0 + vC1) * 0.0625f * m4.x;
            o.y = (vC0 + 2.f * vC1 + vC2) * 0.0625f * m4.y;
            o.z = (vC1 + 2.f * vC2 + vC3) * 0.0625f * m4.z;
            o.w = (vC2 + 2.f * vC3 + vR)  * 0.0625f * m4.w;
            *(float4*)(To + gi) = o;
        }
    } else {
        // ---- slow scalar path (W-edge blocks only) ----
        for (int i = tid; i < RT * SW; i += NT) {
            int r = i / SW, c = i - r * SW;
            int gh = min(max(h0 - 2 + r, 0), H - 1);
            int gw = min(max(w0 - WOFF + c, 0), W - 1);
            sT[r * SW + c] = Tb[(size_t)gh * W + gw];
        }
        __syncthreads();

        for (int i = tid; i < RM * 136; i += NT) {   // cols [w0-4, w0+132)
            int r = i / 136, c = i - r * 136;
            int gh = h0 - 1 + r;
            int gw = w0 - 4 + c;
            int lc = 4 + c;
            float v = 0.0f;
            if (gh >= 0 && gh < H && gw >= 0 && gw < W) {
                int sr  = r + 1;
                int srm = max(gh - 1, 0) - h0 + 2;
                int srp = min(gh + 1, H - 1) - h0 + 2;
                int lcm = max(gw - 1, 0) - w0 + WOFF;
                int lcp = min(gw + 1, W - 1) - w0 + WOFF;
                float tC  = sT[sr * SW + lc];
                float ndx = sT[sr * SW + lcp] - sT[sr * SW + lcm];
                float ndy = sT[srp * SW + lc] - sT[srm * SW + lc];
                float sy = (gh == 0 || gh == H - 1) ? inv_dy : 0.5f * inv_dy;
                float ix = coef[gh];
                float sx = (gw == 0 || gw == W - 1) ? ix : 0.5f * ix;
                size_t gi = (size_t)gh * W + gw;
                float m = mask[gi];
                float F = -(ugb[gi] * (ndx * sx) + vgb[gi] * (ndy * sy)) * m;
                v = tC + DT_S * F;
            }
            sM[r * SW + lc] = v;
        }
        __syncthreads();

        for (int i = tid; i < TH * TW; i += NT) {
            int r = i >> 7, c = i & (TW - 1);
            int gh = h0 + r, gw = w0 + c;
            if (gh < H && gw < W) {
                int lc = WOFF + c, sr = r + 1;
                const float* pU = sM + (sr - 1) * SW + lc;
                const float* pC = sM + sr * SW + lc;
                const float* pD = sM + (sr + 1) * SW + lc;
                float s = (pU[-1] + pU[1] + pD[-1] + pD[1])
                        + 2.f * (pU[0] + pD[0] + pC[-1] + pC[1])
                        + 4.f * pC[0];
                size_t gi = (size_t)gh * W + gw;
                To[gi] = s * 0.0625f * mask[gi];
            }
        }
    }
}

extern "C" void kernel_launch(void* const* d_in, const int* in_sizes, int n_in,
                              void* d_out, int out_size, void* d_ws, size_t ws_size,
                              hipStream_t stream) {
    const float* T0   = (const float*)d_in[0];
    const float* ug   = (const float*)d_in[1];
    const float* vg   = (const float*)d_in[2];
    const float* lat  = (const float*)d_in[3];
    const float* lon  = (const float*)d_in[4];
    const float* mask = (const float*)d_in[5];

    const int H = in_sizes[3];
    const int W = in_sizes[4];
    const int B = in_sizes[0] / (H * W);

    float* out  = (float*)d_out;
    float* ping = (float*)d_ws;                 // B*H*W floats
    float* coef = ping + (size_t)B * H * W;     // H+1 floats: 1/dx[h], then 1/dy

    prep_kernel<<<dim3((H + NT - 1) / NT), dim3(NT), 0, stream>>>(lat, lon, coef, H);

    dim3 grid((W + TW - 1) / TW, (H + TH - 1) / TH, B);
    const int STEPS = 48;
    for (int i = 0; i < STEPS; ++i) {
        const float* src = (i == 0) ? T0 : ((i & 1) ? ping : out);
        float*       dst = (i & 1) ? out : ping;
        step_kernel<<<grid, dim3(NT), 0, stream>>>(src, ug, vg, mask, coef, dst, H, W);
    }
}

// Round 4
// 1605.016 us; speedup vs baseline: 2.5610x; 1.2396x over previous
//
#include <hip/hip_runtime.h>

// Ocean advection + 3x3 binomial smoothing, 48 steps, fp32.
// Barrier-free register-streaming kernel: each 64-lane wave owns a 256-col x
// 8-row strip (one float4 column per lane), marches down H with rolling
// registers (T rows r-1..r+1 -> advected rows r-1..r+1 -> separable smooth).
// X-neighbors via __shfl; inter-block 1-col halo recomputed from broadcast
// loads. No LDS, no __syncthreads.

#define DEG2RAD 0.017453292519943295f
#define R_EARTH 6371000.0f
#define DT_S 600.0f

constexpr int NT    = 256;   // 4 waves / block
constexpr int STRIP = 8;     // output rows per wave
constexpr int WPW   = 256;   // cols per wave (64 lanes x float4)

__global__ __launch_bounds__(256)
void prep_kernel(const float* __restrict__ lat, const float* __restrict__ lon,
                 float* __restrict__ coef, int H) {
    int h = blockIdx.x * blockDim.x + threadIdx.x;
    if (h < H) {
        float dlon = lon[1] - lon[0];
        coef[h] = 1.0f / (R_EARTH * DEG2RAD * dlon * cosf(lat[h] * DEG2RAD));
    }
    if (h == 0) {
        float dlat = lat[1] - lat[0];
        coef[H] = 1.0f / (R_EARTH * DEG2RAD * dlat);
    }
}

__global__ __launch_bounds__(256, 4)
void stream_kernel(const float* __restrict__ Tin, const float* __restrict__ ug,
                   const float* __restrict__ vg, const float* __restrict__ mask,
                   const float* __restrict__ coef, float* __restrict__ Tout,
                   int H, int W) {
    const int lane = threadIdx.x & 63;
    const int wv   = threadIdx.x >> 6;
    const int ws   = blockIdx.x * WPW;
    const int hs   = (blockIdx.y * 4 + wv) * STRIP;
    const int b    = blockIdx.z;
    if (hs >= H) return;
    const size_t plane = (size_t)H * W;
    const float* __restrict__ Tb  = Tin + b * plane;
    const float* __restrict__ ugb = ug  + b * plane;
    const float* __restrict__ vgb = vg  + b * plane;
    float* __restrict__ To = Tout + b * plane;
    const float inv_dy = coef[H];
    const bool atL = (ws == 0);
    const bool atR = (ws + WPW >= W);
    const bool isL = (lane == 0);
    const bool isR = (lane == 63);
    const int gw = ws + 4 * lane;

    auto clampr = [&](int r) { return min(max(r, 0), H - 1); };
    auto ldT = [&](int r) -> float4 {
        return *(const float4*)(Tb + (size_t)clampr(r) * W + gw);
    };
    auto ldL = [&](int r) -> float2 {   // (T[ws-2], T[ws-1]) at clamped row
        float4 q = *(const float4*)(Tb + (size_t)clampr(r) * W + (ws - 4));
        return make_float2(q.z, q.w);
    };
    auto ldR = [&](int r) -> float2 {   // (T[ws+256], T[ws+257]) at clamped row
        float4 q = *(const float4*)(Tb + (size_t)clampr(r) * W + (ws + WPW));
        return make_float2(q.x, q.y);
    };

    // rolling T state
    float4 tp, tc, tn;                       // rows r-1, r, r+1 (clamped)
    float  tLp_w = 0.f; float2 tLc = make_float2(0.f, 0.f), tLn = make_float2(0.f, 0.f);
    float  tRp_x = 0.f; float2 tRc = make_float2(0.f, 0.f), tRn = make_float2(0.f, 0.f);

    auto roll = [&](int rnext) {             // after: tn = row rnext
        tp = tc; tc = tn; tn = ldT(rnext);
        if (!atL) { tLp_w = tLc.y; tLc = tLn; tLn = ldL(rnext); }
        if (!atR) { tRp_x = tRc.x; tRc = tRn; tRn = ldR(rnext); }
    };

    // advect row r (uses tp/tc/tn = rows r-1,r,r+1); zeros outside domain
    auto advrow = [&](int r, float4& a, float& aL, float& aR, float4& mOut) {
        if (r < 0 || r >= H) {
            a = make_float4(0.f, 0.f, 0.f, 0.f); aL = 0.f; aR = 0.f;
            mOut = make_float4(0.f, 0.f, 0.f, 0.f); return;
        }
        const size_t ro = (size_t)r * W;
        const float ix  = coef[r];
        const float sy  = (r == 0 || r == H - 1) ? inv_dy : 0.5f * inv_dy;
        const float sxh = 0.5f * ix;
        float4 u4 = *(const float4*)(ugb + ro + gw);
        float4 g4 = *(const float4*)(vgb + ro + gw);
        float4 m4 = *(const float4*)(mask + ro + gw);
        float cLw = __shfl_up(tc.w, 1);
        float cRx = __shfl_down(tc.x, 1);
        float sxx = sxh, sxw = sxh;
        if (isL) { if (atL) { cLw = tc.x; sxx = ix; } else { cLw = tLc.y; } }
        if (isR) { if (atR) { cRx = tc.w; sxw = ix; } else { cRx = tRc.x; } }
        a.x = tc.x + DT_S * (-(u4.x * ((tc.y - cLw) * sxx) + g4.x * ((tn.x - tp.x) * sy)) * m4.x);
        a.y = tc.y + DT_S * (-(u4.y * ((tc.z - tc.x) * sxh) + g4.y * ((tn.y - tp.y) * sy)) * m4.y);
        a.z = tc.z + DT_S * (-(u4.z * ((tc.w - tc.y) * sxh) + g4.z * ((tn.z - tp.z) * sy)) * m4.z);
        a.w = tc.w + DT_S * (-(u4.w * ((cRx - tc.z) * sxw) + g4.w * ((tn.w - tp.w) * sy)) * m4.w);
        if (!atL) {   // halo col ws-1 (valid on lane 0: tc.x there is T[r][ws])
            float uL = ((const float4*)(ugb + ro + (ws - 4)))->w;
            float gL = ((const float4*)(vgb + ro + (ws - 4)))->w;
            float mL = ((const float4*)(mask + ro + (ws - 4)))->w;
            aL = tLc.y + DT_S * (-(uL * ((tc.x - tLc.x) * sxh) + gL * ((tLn.y - tLp_w) * sy)) * mL);
        } else aL = 0.f;
        if (!atR) {   // halo col ws+256 (valid on lane 63: tc.w there is T[r][ws+255])
            float uR = ((const float4*)(ugb + ro + (ws + WPW)))->x;
            float gR = ((const float4*)(vgb + ro + (ws + WPW)))->x;
            float mR = ((const float4*)(mask + ro + (ws + WPW)))->x;
            aR = tRc.x + DT_S * (-(uR * ((tRc.y - tc.w) * sxh) + gR * ((tRn.x - tRp_x) * sy)) * mR);
        } else aR = 0.f;
        mOut = m4;
    };

    // warm-up: load rows hs-2..hs, advect rows hs-1 and hs
    tp = ldT(hs - 2); tc = ldT(hs - 1); tn = ldT(hs);
    if (!atL) { float2 q = ldL(hs - 2); tLp_w = q.y; tLc = ldL(hs - 1); tLn = ldL(hs); }
    if (!atR) { float2 q = ldR(hs - 2); tRp_x = q.x; tRc = ldR(hs - 1); tRn = ldR(hs); }

    float4 ap, ac, an, mC, mN, mdum;
    float aLp, aLc, aLn, aRp, aRc, aRn;
    advrow(hs - 1, ap, aLp, aRp, mdum);
    roll(hs + 1);
    advrow(hs, ac, aLc, aRc, mC);

    #pragma unroll
    for (int i = 0; i < STRIP; ++i) {
        const int go = hs + i;
        roll(go + 2);
        advrow(go + 1, an, aLn, aRn, mN);
        if (go < H) {
            float4 v;
            v.x = ap.x + 2.f * ac.x + an.x;
            v.y = ap.y + 2.f * ac.y + an.y;
            v.z = ap.z + 2.f * ac.z + an.z;
            v.w = ap.w + 2.f * ac.w + an.w;
            float vL  = aLp + 2.f * aLc + aLn;
            float vR  = aRp + 2.f * aRc + aRn;
            float vLw = __shfl_up(v.w, 1);
            float vRx = __shfl_down(v.x, 1);
            if (isL) vLw = atL ? 0.f : vL;
            if (isR) vRx = atR ? 0.f : vR;
            float4 o;
            o.x = (vLw + 2.f * v.x + v.y) * 0.0625f * mC.x;
            o.y = (v.x + 2.f * v.y + v.z) * 0.0625f * mC.y;
            o.z = (v.y + 2.f * v.z + v.w) * 0.0625f * mC.z;
            o.w = (v.z + 2.f * v.w + vRx) * 0.0625f * mC.w;
            *(float4*)(To + (size_t)go * W + gw) = o;
        }
        ap = ac; ac = an;
        aLp = aLc; aLc = aLn; aRp = aRc; aRc = aRn;
        mC = mN;
    }
}

// ---------- generic fallback (round-1 LDS tile kernel, validated) ----------
constexpr int FTW = 64, FTH = 32;
constexpr int FSTW = FTW + 4, FSTH = FTH + 4;
constexpr int FMTW = FTW + 2, FMTH = FTH + 2;

__global__ __launch_bounds__(256)
void step_tile(const float* __restrict__ Tin, const float* __restrict__ ug,
               const float* __restrict__ vg, const float* __restrict__ mask,
               const float* __restrict__ coef, float* __restrict__ Tout,
               int H, int W) {
    __shared__ float sT[FSTH][FSTW];
    __shared__ float sM[FMTH][FMTW];
    const int tid = threadIdx.x;
    const int w0 = blockIdx.x * FTW;
    const int h0 = blockIdx.y * FTH;
    const int b  = blockIdx.z;
    const long plane = (long)H * W;
    const float* Tb  = Tin + b * plane;
    const float* ugb = ug  + b * plane;
    const float* vgb = vg  + b * plane;
    const float inv_dy = coef[H];

    for (int i = tid; i < FSTH * FSTW; i += NT) {
        int r = i / FSTW, c = i - r * FSTW;
        int gh = min(max(h0 - 2 + r, 0), H - 1);
        int gw = min(max(w0 - 2 + c, 0), W - 1);
        sT[r][c] = Tb[gh * W + gw];
    }
    __syncthreads();
    for (int i = tid; i < FMTH * FMTW; i += NT) {
        int r = i / FMTW, c = i - r * FMTW;
        int gh = h0 - 1 + r, gw = w0 - 1 + c;
        float v = 0.0f;
        if (gh >= 0 && gh < H && gw >= 0 && gw < W) {
            int sr = r + 1, sc = c + 1;
            float ndy = sT[sr + 1][sc] - sT[sr - 1][sc];
            float ndx = sT[sr][sc + 1] - sT[sr][sc - 1];
            float sy  = (gh == 0 || gh == H - 1) ? inv_dy : 0.5f * inv_dy;
            float ix  = coef[gh];
            float sx  = (gw == 0 || gw == W - 1) ? ix : 0.5f * ix;
            int   gi  = gh * W + gw;
            float F   = -(ugb[gi] * (ndx * sx) + vgb[gi] * (ndy * sy)) * mask[gi];
            v = sT[sr][sc] + DT_S * F;
        }
        sM[r][c] = v;
    }
    __syncthreads();
    float* To = Tout + b * plane;
    for (int i = tid; i < FTH * FTW; i += NT) {
        int r = i >> 6, c = i & (FTW - 1);
        int gh = h0 + r, gw = w0 + c;
        if (gh < H && gw < W) {
            int sr = r + 1, sc = c + 1;
            float s = (sM[sr-1][sc-1] + sM[sr-1][sc+1] + sM[sr+1][sc-1] + sM[sr+1][sc+1])
                    + 2.0f * (sM[sr-1][sc] + sM[sr+1][sc] + sM[sr][sc-1] + sM[sr][sc+1])
                    + 4.0f * sM[sr][sc];
            To[gh * W + gw] = s * 0.0625f * mask[gh * W + gw];
        }
    }
}

extern "C" void kernel_launch(void* const* d_in, const int* in_sizes, int n_in,
                              void* d_out, int out_size, void* d_ws, size_t ws_size,
                              hipStream_t stream) {
    const float* T0   = (const float*)d_in[0];
    const float* ug   = (const float*)d_in[1];
    const float* vg   = (const float*)d_in[2];
    const float* lat  = (const float*)d_in[3];
    const float* lon  = (const float*)d_in[4];
    const float* mask = (const float*)d_in[5];

    const int H = in_sizes[3];
    const int W = in_sizes[4];
    const int B = in_sizes[0] / (H * W);

    float* out  = (float*)d_out;
    float* ping = (float*)d_ws;                 // B*H*W floats
    float* coef = ping + (size_t)B * H * W;     // H+1 floats: 1/dx[h], then 1/dy

    prep_kernel<<<dim3((H + NT - 1) / NT), dim3(NT), 0, stream>>>(lat, lon, coef, H);

    const bool fast = (W % WPW) == 0;
    dim3 gridS(W / (fast ? WPW : 1), (H + 4 * STRIP - 1) / (4 * STRIP), B);
    dim3 gridF((W + FTW - 1) / FTW, (H + FTH - 1) / FTH, B);

    const int STEPS = 48;
    for (int i = 0; i < STEPS; ++i) {
        const float* src = (i == 0) ? T0 : ((i & 1) ? ping : out);
        float*       dst = (i & 1) ? out : ping;
        if (fast)
            stream_kernel<<<gridS, dim3(NT), 0, stream>>>(src, ug, vg, mask, coef, dst, H, W);
        else
            step_tile<<<gridF, dim3(NT), 0, stream>>>(src, ug, vg, mask, coef, dst, H, W);
    }
}